// Round 2
// baseline (814.686 us; speedup 1.0000x reference)
//
#include <hip/hip_runtime.h>

// LJ reduced units: sigma=1, eps=1, cutoff=2.5
// e_pair = 4*(sr6^2 - sr6) - SHIFT, SHIFT = -0.0163168896
// half  = 0.5*e_pair = 2*(sr6^2 - sr6) + 0.0081584448
__device__ __forceinline__ float half_lj(float r2) {
    float sr2 = 1.0f / r2;
    float sr6 = sr2 * sr2 * sr2;
    return fmaf(2.0f, sr6 * sr6 - sr6, 0.0081584448f);
}

// Physical XCD id of the CU this wave runs on (0..7 on MI355X).
// HW-verified on gfx950 (learn_hip m09).
__device__ __forceinline__ int xcc_id() {
    int x;
    asm volatile("s_getreg_b32 %0, hwreg(HW_REG_XCC_ID)" : "=s"(x));
    return x & 7;
}

// No-return, non-coherent f32 atomic add: executes in the XCD-local L2
// (no sc0 = no return, no sc1 = not forced to the device coherence point).
// Safe ONLY because each replica is touched by exactly one XCD (partitioned
// by the real XCC_ID above), and kernel-end release flushes L2 dirty lines
// before the reduce kernel runs.
__device__ __forceinline__ void l2_fadd(float* p, float v) {
    asm volatile("global_atomic_add_f32 %0, %1, off" :: "v"(p), "v"(v) : "memory");
}

// One thread handles 4 pairs: 2x int4 (pairs) + 3x float4 (distances),
// 16B-aligned, fully coalesced. 8 L2-local atomics into this XCD's replica.
__global__ void lj_vec4_ws_kernel(const int4* __restrict__ pairs4,
                                  const float4* __restrict__ dist4,
                                  float* __restrict__ ws,
                                  int npair4, int n_atoms) {
    int t = blockIdx.x * blockDim.x + threadIdx.x;
    if (t >= npair4) return;

    float* rep = ws + (size_t)xcc_id() * (size_t)n_atoms;

    int4 p01 = pairs4[2 * t];
    int4 p23 = pairs4[2 * t + 1];
    float4 d0 = dist4[3 * t];
    float4 d1 = dist4[3 * t + 1];
    float4 d2 = dist4[3 * t + 2];

    float r2_0 = fmaf(d0.x, d0.x, fmaf(d0.y, d0.y, d0.z * d0.z));
    float r2_1 = fmaf(d0.w, d0.w, fmaf(d1.x, d1.x, d1.y * d1.y));
    float r2_2 = fmaf(d1.z, d1.z, fmaf(d1.w, d1.w, d2.x * d2.x));
    float r2_3 = fmaf(d2.y, d2.y, fmaf(d2.z, d2.z, d2.w * d2.w));

    float h0 = half_lj(r2_0);
    float h1 = half_lj(r2_1);
    float h2 = half_lj(r2_2);
    float h3 = half_lj(r2_3);

    l2_fadd(&rep[p01.x], h0);
    l2_fadd(&rep[p01.y], h0);
    l2_fadd(&rep[p01.z], h1);
    l2_fadd(&rep[p01.w], h1);
    l2_fadd(&rep[p23.x], h2);
    l2_fadd(&rep[p23.y], h2);
    l2_fadd(&rep[p23.z], h3);
    l2_fadd(&rep[p23.w], h3);
}

// Tail (npairs % 4): same replica scheme, one small block.
__global__ void lj_tail_ws_kernel(const int* __restrict__ pairs,
                                  const float* __restrict__ dist,
                                  float* __restrict__ ws,
                                  int start, int npairs, int n_atoms) {
    int i = start + blockIdx.x * blockDim.x + threadIdx.x;
    if (i >= npairs) return;
    float* rep = ws + (size_t)xcc_id() * (size_t)n_atoms;
    float dx = dist[3 * i + 0];
    float dy = dist[3 * i + 1];
    float dz = dist[3 * i + 2];
    float h = half_lj(fmaf(dx, dx, fmaf(dy, dy, dz * dz)));
    l2_fadd(&rep[pairs[2 * i + 0]], h);
    l2_fadd(&rep[pairs[2 * i + 1]], h);
}

// out[i] = sum over the 8 replicas. float4 per thread, coalesced.
__global__ void reduce_reps_kernel(const float4* __restrict__ ws,
                                   float4* __restrict__ out,
                                   int n4, int nrep) {
    int i = blockIdx.x * blockDim.x + threadIdx.x;
    if (i >= n4) return;
    float4 s = ws[i];
    for (int r = 1; r < nrep; ++r) {
        float4 v = ws[(size_t)r * n4 + i];
        s.x += v.x; s.y += v.y; s.z += v.z; s.w += v.w;
    }
    out[i] = s;
}

// Fallback if ws is too small: agent-scope native fp atomics straight to out.
__global__ void lj_vec4_agent_kernel(const int4* __restrict__ pairs4,
                                     const float4* __restrict__ dist4,
                                     float* __restrict__ out,
                                     int npair4) {
    int t = blockIdx.x * blockDim.x + threadIdx.x;
    if (t >= npair4) return;
    int4 p01 = pairs4[2 * t];
    int4 p23 = pairs4[2 * t + 1];
    float4 d0 = dist4[3 * t];
    float4 d1 = dist4[3 * t + 1];
    float4 d2 = dist4[3 * t + 2];
    float h0 = half_lj(fmaf(d0.x, d0.x, fmaf(d0.y, d0.y, d0.z * d0.z)));
    float h1 = half_lj(fmaf(d0.w, d0.w, fmaf(d1.x, d1.x, d1.y * d1.y)));
    float h2 = half_lj(fmaf(d1.z, d1.z, fmaf(d1.w, d1.w, d2.x * d2.x)));
    float h3 = half_lj(fmaf(d2.y, d2.y, fmaf(d2.z, d2.z, d2.w * d2.w)));
    unsafeAtomicAdd(&out[p01.x], h0);
    unsafeAtomicAdd(&out[p01.y], h0);
    unsafeAtomicAdd(&out[p01.z], h1);
    unsafeAtomicAdd(&out[p01.w], h1);
    unsafeAtomicAdd(&out[p23.x], h2);
    unsafeAtomicAdd(&out[p23.y], h2);
    unsafeAtomicAdd(&out[p23.z], h3);
    unsafeAtomicAdd(&out[p23.w], h3);
}

extern "C" void kernel_launch(void* const* d_in, const int* in_sizes, int n_in,
                              void* d_out, int out_size, void* d_ws, size_t ws_size,
                              hipStream_t stream) {
    const int* pairs = (const int*)d_in[0];      // [P, 2] int32
    const float* dist = (const float*)d_in[1];   // [P, 3] float32
    float* out = (float*)d_out;                  // [n_atoms] float32

    const int n_atoms = out_size;
    const int npairs = in_sizes[0] / 2;
    const int npair4 = npairs / 4;
    const int tail_start = npair4 * 4;
    const int ntail = npairs - tail_start;

    const int NREP = 8;
    const size_t ws_need = (size_t)NREP * (size_t)n_atoms * sizeof(float);

    if (ws_size >= ws_need && (n_atoms % 4) == 0) {
        float* ws = (float*)d_ws;
        // Zero the 8 per-XCD replicas.
        hipMemsetAsync(d_ws, 0, ws_need, stream);

        if (npair4 > 0) {
            int block = 256;
            int grid = (npair4 + block - 1) / block;
            lj_vec4_ws_kernel<<<grid, block, 0, stream>>>(
                (const int4*)pairs, (const float4*)dist, ws, npair4, n_atoms);
        }
        if (ntail > 0) {
            lj_tail_ws_kernel<<<1, 64, 0, stream>>>(pairs, dist, ws,
                                                    tail_start, npairs, n_atoms);
        }
        int n4 = n_atoms / 4;
        int block = 256;
        int grid = (n4 + block - 1) / block;
        reduce_reps_kernel<<<grid, block, 0, stream>>>(
            (const float4*)ws, (float4*)out, n4, NREP);
    } else {
        // Fallback: agent-scope native fp atomics on the output.
        hipMemsetAsync(d_out, 0, (size_t)out_size * sizeof(float), stream);
        if (npair4 > 0) {
            int block = 256;
            int grid = (npair4 + block - 1) / block;
            lj_vec4_agent_kernel<<<grid, block, 0, stream>>>(
                (const int4*)pairs, (const float4*)dist, out, npair4);
        }
        if (ntail > 0) {
            // tail via safe device atomics (tiny)
            lj_tail_ws_kernel<<<1, 64, 0, stream>>>(pairs, dist, out, 0 + tail_start,
                                                    npairs, 0);
        }
    }
}

// Round 3
// 152.236 us; speedup vs baseline: 5.3515x; 5.3515x over previous
//
#include <hip/hip_runtime.h>

// LJ reduced units: sigma=1, eps=1, cutoff=2.5
// e_pair = 4*(sr6^2 - sr6) - SHIFT, SHIFT = -0.0163168896
// half  = 0.5*e_pair = 2*(sr6^2 - sr6) + 0.0081584448
__device__ __forceinline__ float half_lj(float r2) {
    float sr2 = 1.0f / r2;
    float sr6 = sr2 * sr2 * sr2;
    return fmaf(2.0f, sr6 * sr6 - sr6, 0.0081584448f);
}

#define SLICE_SHIFT 15
#define SLICE_SZ 32768   // atoms per slice -> 128 KB LDS (fits 160 KB/CU)

// ---------------- K1: per-pair half energies ----------------
// One thread = 4 pairs: 3x float4 distance loads -> 1x float4 e store.
__global__ void compute_e_kernel(const float4* __restrict__ dist4,
                                 float4* __restrict__ e4, int npair4) {
    int t = blockIdx.x * blockDim.x + threadIdx.x;
    if (t >= npair4) return;
    float4 d0 = dist4[3 * t];
    float4 d1 = dist4[3 * t + 1];
    float4 d2 = dist4[3 * t + 2];
    float4 e;
    e.x = half_lj(fmaf(d0.x, d0.x, fmaf(d0.y, d0.y, d0.z * d0.z)));
    e.y = half_lj(fmaf(d0.w, d0.w, fmaf(d1.x, d1.x, d1.y * d1.y)));
    e.z = half_lj(fmaf(d1.z, d1.z, fmaf(d1.w, d1.w, d2.x * d2.x)));
    e.w = half_lj(fmaf(d2.y, d2.y, fmaf(d2.z, d2.z, d2.w * d2.w)));
    e4[t] = e;
}

__global__ void compute_e_tail_kernel(const float* __restrict__ dist,
                                      float* __restrict__ e,
                                      int start, int npairs) {
    int i = start + blockIdx.x * blockDim.x + threadIdx.x;
    if (i >= npairs) return;
    float dx = dist[3 * i], dy = dist[3 * i + 1], dz = dist[3 * i + 2];
    e[i] = half_lj(fmaf(dx, dx, fmaf(dy, dy, dz * dz)));
}

// ---------------- K2: slice accumulate in LDS ----------------
// Grid = nslices * B. Block (s,b): stream chunk b of (pairs, e); LDS-atomic
// slice-s hits; plain-store the 128 KB slice into replica b (no global atomics).
__global__ __launch_bounds__(1024, 1)
void accum_slice_kernel(const int4* __restrict__ pairs4,
                        const float4* __restrict__ e4,
                        const int* __restrict__ pairs,
                        const float* __restrict__ e,
                        float* __restrict__ rep,
                        int npair4, int npairs, int nslices, int B, int n_pad) {
    __shared__ float lds[SLICE_SZ];
    const int s = blockIdx.x % nslices;
    const int b = blockIdx.x / nslices;
    const int tid = threadIdx.x;

    // zero LDS
    float4* lds4 = (float4*)lds;
    for (int i = tid; i < SLICE_SZ / 4; i += 1024)
        lds4[i] = make_float4(0.f, 0.f, 0.f, 0.f);
    __syncthreads();

    // quad-pair chunk [qb, qe)
    const int qb = (int)((long long)b * npair4 / B);
    const int qe = (int)((long long)(b + 1) * npair4 / B);
    const unsigned us = (unsigned)s;

    for (int q = qb + tid; q < qe; q += 1024) {
        int4 pA = pairs4[2 * q];
        int4 pB = pairs4[2 * q + 1];
        float4 ev = e4[q];
        if (((unsigned)pA.x >> SLICE_SHIFT) == us) atomicAdd(&lds[pA.x & (SLICE_SZ - 1)], ev.x);
        if (((unsigned)pA.y >> SLICE_SHIFT) == us) atomicAdd(&lds[pA.y & (SLICE_SZ - 1)], ev.x);
        if (((unsigned)pA.z >> SLICE_SHIFT) == us) atomicAdd(&lds[pA.z & (SLICE_SZ - 1)], ev.y);
        if (((unsigned)pA.w >> SLICE_SHIFT) == us) atomicAdd(&lds[pA.w & (SLICE_SZ - 1)], ev.y);
        if (((unsigned)pB.x >> SLICE_SHIFT) == us) atomicAdd(&lds[pB.x & (SLICE_SZ - 1)], ev.z);
        if (((unsigned)pB.y >> SLICE_SHIFT) == us) atomicAdd(&lds[pB.y & (SLICE_SZ - 1)], ev.z);
        if (((unsigned)pB.z >> SLICE_SHIFT) == us) atomicAdd(&lds[pB.z & (SLICE_SZ - 1)], ev.w);
        if (((unsigned)pB.w >> SLICE_SHIFT) == us) atomicAdd(&lds[pB.w & (SLICE_SZ - 1)], ev.w);
    }

    // global tail pairs (npairs % 4), handled by chunk b == 0 for each slice
    if (b == 0) {
        for (int i = npair4 * 4 + tid; i < npairs; i += 1024) {
            int a0 = pairs[2 * i], a1 = pairs[2 * i + 1];
            float h = e[i];
            if (((unsigned)a0 >> SLICE_SHIFT) == us) atomicAdd(&lds[a0 & (SLICE_SZ - 1)], h);
            if (((unsigned)a1 >> SLICE_SHIFT) == us) atomicAdd(&lds[a1 & (SLICE_SZ - 1)], h);
        }
    }
    __syncthreads();

    // flush: plain coalesced stores into replica b (exclusive region)
    float4* rep4 = (float4*)(rep + (size_t)b * n_pad + (size_t)s * SLICE_SZ);
    for (int i = tid; i < SLICE_SZ / 4; i += 1024)
        rep4[i] = lds4[i];
}

// ---------------- K3: reduce replicas ----------------
__global__ void reduce_reps_kernel(const float* __restrict__ rep,
                                   float* __restrict__ out,
                                   int n_atoms, int n_pad, int B) {
    int i4 = blockIdx.x * blockDim.x + threadIdx.x;
    int n4 = n_atoms / 4;
    if (i4 < n4) {
        float4 sum = make_float4(0.f, 0.f, 0.f, 0.f);
        for (int b = 0; b < B; ++b) {
            float4 v = *(const float4*)(rep + (size_t)b * n_pad + 4 * (size_t)i4);
            sum.x += v.x; sum.y += v.y; sum.z += v.z; sum.w += v.w;
        }
        ((float4*)out)[i4] = sum;
    }
    // scalar tail (n_atoms % 4)
    if (i4 == 0) {
        for (int i = n4 * 4; i < n_atoms; ++i) {
            float sum = 0.f;
            for (int b = 0; b < B; ++b) sum += rep[(size_t)b * n_pad + i];
            out[i] = sum;
        }
    }
}

// ---------------- fallback: direct agent-scope atomics ----------------
__global__ void lj_vec4_agent_kernel(const int4* __restrict__ pairs4,
                                     const float4* __restrict__ dist4,
                                     float* __restrict__ out, int npair4) {
    int t = blockIdx.x * blockDim.x + threadIdx.x;
    if (t >= npair4) return;
    int4 p01 = pairs4[2 * t];
    int4 p23 = pairs4[2 * t + 1];
    float4 d0 = dist4[3 * t];
    float4 d1 = dist4[3 * t + 1];
    float4 d2 = dist4[3 * t + 2];
    float h0 = half_lj(fmaf(d0.x, d0.x, fmaf(d0.y, d0.y, d0.z * d0.z)));
    float h1 = half_lj(fmaf(d0.w, d0.w, fmaf(d1.x, d1.x, d1.y * d1.y)));
    float h2 = half_lj(fmaf(d1.z, d1.z, fmaf(d1.w, d1.w, d2.x * d2.x)));
    float h3 = half_lj(fmaf(d2.y, d2.y, fmaf(d2.z, d2.z, d2.w * d2.w)));
    unsafeAtomicAdd(&out[p01.x], h0);
    unsafeAtomicAdd(&out[p01.y], h0);
    unsafeAtomicAdd(&out[p01.z], h1);
    unsafeAtomicAdd(&out[p01.w], h1);
    unsafeAtomicAdd(&out[p23.x], h2);
    unsafeAtomicAdd(&out[p23.y], h2);
    unsafeAtomicAdd(&out[p23.z], h3);
    unsafeAtomicAdd(&out[p23.w], h3);
}

__global__ void lj_tail_agent_kernel(const int* __restrict__ pairs,
                                     const float* __restrict__ dist,
                                     float* __restrict__ out,
                                     int start, int npairs) {
    int i = start + blockIdx.x * blockDim.x + threadIdx.x;
    if (i >= npairs) return;
    float dx = dist[3 * i], dy = dist[3 * i + 1], dz = dist[3 * i + 2];
    float h = half_lj(fmaf(dx, dx, fmaf(dy, dy, dz * dz)));
    unsafeAtomicAdd(&out[pairs[2 * i]], h);
    unsafeAtomicAdd(&out[pairs[2 * i + 1]], h);
}

extern "C" void kernel_launch(void* const* d_in, const int* in_sizes, int n_in,
                              void* d_out, int out_size, void* d_ws, size_t ws_size,
                              hipStream_t stream) {
    const int* pairs = (const int*)d_in[0];      // [P, 2] int32
    const float* dist = (const float*)d_in[1];   // [P, 3] float32
    float* out = (float*)d_out;                  // [n_atoms] float32

    const int n_atoms = out_size;
    const int npairs = in_sizes[0] / 2;
    const int npair4 = npairs / 4;
    const int tail_start = npair4 * 4;
    const int ntail = npairs - tail_start;

    const int nslices = (n_atoms + SLICE_SZ - 1) >> SLICE_SHIFT;
    const int n_pad = nslices << SLICE_SHIFT;

    // ws layout: e[npairs rounded up to 4] | rep[B][n_pad]
    const size_t e_elems = (size_t)(npair4 + (ntail ? 1 : 0)) * 4;
    const size_t e_bytes = e_elems * sizeof(float);
    int B = 32;
    while (B > 8 && e_bytes + (size_t)B * n_pad * sizeof(float) > ws_size) B >>= 1;

    if (e_bytes + (size_t)B * n_pad * sizeof(float) <= ws_size) {
        float* e = (float*)d_ws;
        float* rep = e + e_elems;

        if (npair4 > 0) {
            int block = 256;
            compute_e_kernel<<<(npair4 + block - 1) / block, block, 0, stream>>>(
                (const float4*)dist, (float4*)e, npair4);
        }
        if (ntail > 0) {
            compute_e_tail_kernel<<<1, 64, 0, stream>>>(dist, e, tail_start, npairs);
        }

        accum_slice_kernel<<<nslices * B, 1024, 0, stream>>>(
            (const int4*)pairs, (const float4*)e, pairs, e, rep,
            npair4, npairs, nslices, B, n_pad);

        int n4 = n_atoms / 4;
        int block = 256;
        int grid = (n4 + block - 1) / block;
        if (grid == 0) grid = 1;
        reduce_reps_kernel<<<grid, block, 0, stream>>>(rep, out, n_atoms, n_pad, B);
    } else {
        // fallback: measured 803 us path
        hipMemsetAsync(d_out, 0, (size_t)out_size * sizeof(float), stream);
        if (npair4 > 0) {
            int block = 256;
            lj_vec4_agent_kernel<<<(npair4 + block - 1) / block, block, 0, stream>>>(
                (const int4*)pairs, (const float4*)dist, out, npair4);
        }
        if (ntail > 0) {
            lj_tail_agent_kernel<<<1, 64, 0, stream>>>(pairs, dist, out,
                                                       tail_start, npairs);
        }
    }
}

// Round 4
// 124.951 us; speedup vs baseline: 6.5200x; 1.2184x over previous
//
#include <hip/hip_runtime.h>
#include <hip/hip_fp16.h>

// LJ reduced units: sigma=1, eps=1, cutoff=2.5
// e_pair = 4*(sr6^2 - sr6) - SHIFT, SHIFT = -0.0163168896
// half  = 0.5*e_pair = 2*(sr6^2 - sr6) + 0.0081584448
__device__ __forceinline__ float half_lj(float r2) {
    float sr2 = 1.0f / r2;
    float sr6 = sr2 * sr2 * sr2;
    return fmaf(2.0f, sr6 * sr6 - sr6, 0.0081584448f);
}

#define SLICE_SHIFT 15
#define SLICE_SZ 32768   // atoms per slice -> 128 KB LDS

// ---------------- K1: per-pair half energies (fp16) ----------------
// One thread = 8 pairs: 6x float4 distance loads -> one uint4 (8 halfs) store.
__global__ void compute_e8_kernel(const float4* __restrict__ dist4,
                                  uint4* __restrict__ e8, int npair8) {
    int t = blockIdx.x * blockDim.x + threadIdx.x;
    if (t >= npair8) return;
    float4 v0 = dist4[6 * t + 0], v1 = dist4[6 * t + 1], v2 = dist4[6 * t + 2];
    float4 v3 = dist4[6 * t + 3], v4 = dist4[6 * t + 4], v5 = dist4[6 * t + 5];
    float h0 = half_lj(fmaf(v0.x, v0.x, fmaf(v0.y, v0.y, v0.z * v0.z)));
    float h1 = half_lj(fmaf(v0.w, v0.w, fmaf(v1.x, v1.x, v1.y * v1.y)));
    float h2 = half_lj(fmaf(v1.z, v1.z, fmaf(v1.w, v1.w, v2.x * v2.x)));
    float h3 = half_lj(fmaf(v2.y, v2.y, fmaf(v2.z, v2.z, v2.w * v2.w)));
    float h4 = half_lj(fmaf(v3.x, v3.x, fmaf(v3.y, v3.y, v3.z * v3.z)));
    float h5 = half_lj(fmaf(v3.w, v3.w, fmaf(v4.x, v4.x, v4.y * v4.y)));
    float h6 = half_lj(fmaf(v4.z, v4.z, fmaf(v4.w, v4.w, v5.x * v5.x)));
    float h7 = half_lj(fmaf(v5.y, v5.y, fmaf(v5.z, v5.z, v5.w * v5.w)));
    union { __half2 h; unsigned u; } c01, c23, c45, c67;
    c01.h = __floats2half2_rn(h0, h1);
    c23.h = __floats2half2_rn(h2, h3);
    c45.h = __floats2half2_rn(h4, h5);
    c67.h = __floats2half2_rn(h6, h7);
    uint4 o; o.x = c01.u; o.y = c23.u; o.z = c45.u; o.w = c67.u;
    e8[t] = o;
}

__global__ void compute_e_tail_kernel(const float* __restrict__ dist,
                                      __half* __restrict__ eh,
                                      int start, int npairs) {
    int i = start + blockIdx.x * blockDim.x + threadIdx.x;
    if (i >= npairs) return;
    float dx = dist[3 * i], dy = dist[3 * i + 1], dz = dist[3 * i + 2];
    eh[i] = __float2half(half_lj(fmaf(dx, dx, fmaf(dy, dy, dz * dz))));
}

// ---------------- K2: slice accumulate in LDS ----------------
// Grid = nslices * B (= 256 = #CUs). Block (s,b): stream chunk b of
// (pairs, e[fp16]); LDS-atomic slice-s hits; plain-store slice to replica b.
// Swizzle: the 8 blocks (one per slice) reading chunk b share an XCD
// (round-robin dispatch heuristic) so 7/8 of chunk reads are L2 hits.
__global__ __launch_bounds__(1024, 1)
void accum_slice_kernel(const int4* __restrict__ pairs4,
                        const uint2* __restrict__ eh2,
                        const int* __restrict__ pairs,
                        const __half* __restrict__ eh,
                        float* __restrict__ rep,
                        int npair4, int npairs, int nslices, int B, int n_pad) {
    __shared__ float lds[SLICE_SZ];
    int gid = blockIdx.x;
    int s, b;
    if (nslices == 8 && B == 32) {
        int x = gid & 7, j = gid >> 3;   // x = presumed XCD, j = 0..31
        s = j >> 2;                      // 8 slices
        b = (x << 2) | (j & 3);          // 4 chunks per XCD, shared by 8 slices
    } else {
        s = gid % nslices;
        b = gid / nslices;
    }
    const int tid = threadIdx.x;
    const int base = s << SLICE_SHIFT;

    float4* lds4 = (float4*)lds;
    for (int i = tid; i < SLICE_SZ / 4; i += 1024)
        lds4[i] = make_float4(0.f, 0.f, 0.f, 0.f);
    __syncthreads();

    const int qb = (int)((long long)b * npair4 / B);
    const int qe = (int)((long long)(b + 1) * npair4 / B);

#define CHK(atom, val)                                        \
    do {                                                      \
        int _t = (atom) - base;                               \
        if ((unsigned)_t < SLICE_SZ) atomicAdd(&lds[_t], (val)); \
    } while (0)

#define PROCESS(pA, pB, ue)                                   \
    do {                                                      \
        union { unsigned u; __half2 h; } _a, _b;              \
        _a.u = (ue).x; _b.u = (ue).y;                         \
        float2 _e01 = __half22float2(_a.h);                   \
        float2 _e23 = __half22float2(_b.h);                   \
        CHK((pA).x, _e01.x); CHK((pA).y, _e01.x);             \
        CHK((pA).z, _e01.y); CHK((pA).w, _e01.y);             \
        CHK((pB).x, _e23.x); CHK((pB).y, _e23.x);             \
        CHK((pB).z, _e23.y); CHK((pB).w, _e23.y);             \
    } while (0)

    int q = qb + tid;
    // 2x unrolled with all loads hoisted for ILP
    for (; q + 1024 < qe; q += 2048) {
        int4 pA0 = pairs4[2 * q];
        int4 pB0 = pairs4[2 * q + 1];
        uint2 ue0 = eh2[q];
        int4 pA1 = pairs4[2 * (q + 1024)];
        int4 pB1 = pairs4[2 * (q + 1024) + 1];
        uint2 ue1 = eh2[q + 1024];
        PROCESS(pA0, pB0, ue0);
        PROCESS(pA1, pB1, ue1);
    }
    if (q < qe) {
        int4 pA = pairs4[2 * q];
        int4 pB = pairs4[2 * q + 1];
        uint2 ue = eh2[q];
        PROCESS(pA, pB, ue);
    }

    // scalar tail pairs (npairs % 4): handled once per slice by chunk b==0
    if (b == 0) {
        for (int i = npair4 * 4 + tid; i < npairs; i += 1024) {
            int a0 = pairs[2 * i], a1 = pairs[2 * i + 1];
            float h = __half2float(eh[i]);
            CHK(a0, h);
            CHK(a1, h);
        }
    }
#undef PROCESS
#undef CHK
    __syncthreads();

    float4* rep4 = (float4*)(rep + (size_t)b * n_pad + (size_t)s * SLICE_SZ);
    for (int i = tid; i < SLICE_SZ / 4; i += 1024)
        rep4[i] = lds4[i];
}

// ---------------- K3: reduce replicas ----------------
__global__ void reduce_reps_kernel(const float* __restrict__ rep,
                                   float* __restrict__ out,
                                   int n_atoms, int n_pad, int B) {
    int i4 = blockIdx.x * blockDim.x + threadIdx.x;
    int n4 = n_atoms / 4;
    if (i4 < n4) {
        float4 sum = make_float4(0.f, 0.f, 0.f, 0.f);
        for (int b = 0; b < B; ++b) {
            float4 v = *(const float4*)(rep + (size_t)b * n_pad + 4 * (size_t)i4);
            sum.x += v.x; sum.y += v.y; sum.z += v.z; sum.w += v.w;
        }
        ((float4*)out)[i4] = sum;
    }
    if (i4 == 0) {
        for (int i = n4 * 4; i < n_atoms; ++i) {
            float sum = 0.f;
            for (int b = 0; b < B; ++b) sum += rep[(size_t)b * n_pad + i];
            out[i] = sum;
        }
    }
}

// ---------------- fallback: direct agent-scope atomics ----------------
__global__ void lj_vec4_agent_kernel(const int4* __restrict__ pairs4,
                                     const float4* __restrict__ dist4,
                                     float* __restrict__ out, int npair4) {
    int t = blockIdx.x * blockDim.x + threadIdx.x;
    if (t >= npair4) return;
    int4 p01 = pairs4[2 * t];
    int4 p23 = pairs4[2 * t + 1];
    float4 d0 = dist4[3 * t];
    float4 d1 = dist4[3 * t + 1];
    float4 d2 = dist4[3 * t + 2];
    float h0 = half_lj(fmaf(d0.x, d0.x, fmaf(d0.y, d0.y, d0.z * d0.z)));
    float h1 = half_lj(fmaf(d0.w, d0.w, fmaf(d1.x, d1.x, d1.y * d1.y)));
    float h2 = half_lj(fmaf(d1.z, d1.z, fmaf(d1.w, d1.w, d2.x * d2.x)));
    float h3 = half_lj(fmaf(d2.y, d2.y, fmaf(d2.z, d2.z, d2.w * d2.w)));
    unsafeAtomicAdd(&out[p01.x], h0);
    unsafeAtomicAdd(&out[p01.y], h0);
    unsafeAtomicAdd(&out[p01.z], h1);
    unsafeAtomicAdd(&out[p01.w], h1);
    unsafeAtomicAdd(&out[p23.x], h2);
    unsafeAtomicAdd(&out[p23.y], h2);
    unsafeAtomicAdd(&out[p23.z], h3);
    unsafeAtomicAdd(&out[p23.w], h3);
}

__global__ void lj_tail_agent_kernel(const int* __restrict__ pairs,
                                     const float* __restrict__ dist,
                                     float* __restrict__ out,
                                     int start, int npairs) {
    int i = start + blockIdx.x * blockDim.x + threadIdx.x;
    if (i >= npairs) return;
    float dx = dist[3 * i], dy = dist[3 * i + 1], dz = dist[3 * i + 2];
    float h = half_lj(fmaf(dx, dx, fmaf(dy, dy, dz * dz)));
    unsafeAtomicAdd(&out[pairs[2 * i]], h);
    unsafeAtomicAdd(&out[pairs[2 * i + 1]], h);
}

extern "C" void kernel_launch(void* const* d_in, const int* in_sizes, int n_in,
                              void* d_out, int out_size, void* d_ws, size_t ws_size,
                              hipStream_t stream) {
    const int* pairs = (const int*)d_in[0];      // [P, 2] int32
    const float* dist = (const float*)d_in[1];   // [P, 3] float32
    float* out = (float*)d_out;                  // [n_atoms] float32

    const int n_atoms = out_size;
    const int npairs = in_sizes[0] / 2;
    const int npair4 = npairs / 4;
    const int npair8 = npairs / 8;

    const int nslices = (n_atoms + SLICE_SZ - 1) >> SLICE_SHIFT;
    const int n_pad = nslices << SLICE_SHIFT;

    // ws layout: eh[npairs rounded to 8, fp16] | rep[B][n_pad] f32
    const size_t e_elems = (size_t)((npairs + 7) / 8) * 8;
    const size_t e_bytes = e_elems * sizeof(__half);   // 16B-aligned
    int B = 32;
    while (B > 8 && e_bytes + (size_t)B * n_pad * sizeof(float) > ws_size) B >>= 1;

    if (e_bytes + (size_t)B * n_pad * sizeof(float) <= ws_size) {
        __half* eh = (__half*)d_ws;
        float* rep = (float*)((char*)d_ws + e_bytes);

        if (npair8 > 0) {
            int block = 256;
            compute_e8_kernel<<<(npair8 + block - 1) / block, block, 0, stream>>>(
                (const float4*)dist, (uint4*)eh, npair8);
        }
        if (npair8 * 8 < npairs) {
            compute_e_tail_kernel<<<1, 64, 0, stream>>>(dist, eh, npair8 * 8, npairs);
        }

        accum_slice_kernel<<<nslices * B, 1024, 0, stream>>>(
            (const int4*)pairs, (const uint2*)eh, pairs, eh, rep,
            npair4, npairs, nslices, B, n_pad);

        int n4 = n_atoms / 4;
        int block = 256;
        int grid = (n4 + block - 1) / block;
        if (grid == 0) grid = 1;
        reduce_reps_kernel<<<grid, block, 0, stream>>>(rep, out, n_atoms, n_pad, B);
    } else {
        // fallback: measured 803 us device-atomic path
        hipMemsetAsync(d_out, 0, (size_t)out_size * sizeof(float), stream);
        if (npair4 > 0) {
            int block = 256;
            lj_vec4_agent_kernel<<<(npair4 + block - 1) / block, block, 0, stream>>>(
                (const int4*)pairs, (const float4*)dist, out, npair4);
        }
        if (npair4 * 4 < npairs) {
            lj_tail_agent_kernel<<<1, 64, 0, stream>>>(pairs, dist, out,
                                                       npair4 * 4, npairs);
        }
    }
}